// Round 7
// baseline (9234.177 us; speedup 1.0000x reference)
//
#include <hip/hip_runtime.h>

#define N_USERS 100000
#define N_ITEMS 50000
#define N_TOTAL 150000
#define EMB 64
#define NNZ_CONST 8000000

// bucketing: 64 rows per bucket
#define BSHIFT 6
#define ROWS_PER_BUCKET 64
#define BUCKETS 2344            // ceil(150000/64); 2344*4 = 9376 B LDS hist
#define LACC_STRIDE 68          // 64 dims + 4 pad floats (bank spread)

typedef unsigned short u16;
typedef unsigned int u32;
typedef unsigned long long u64;

// f32 -> bf16 round-to-nearest-even
__device__ __forceinline__ u16 f32_to_bf16(float f) {
    u32 b = __float_as_uint(f);
    b += 0x7FFFu + ((b >> 16) & 1u);
    return (u16)(b >> 16);
}
__device__ __forceinline__ float bf16lo_to_f32(u32 w) {
    return __uint_as_float(w << 16);
}
__device__ __forceinline__ float bf16hi_to_f32(u32 w) {
    return __uint_as_float(w & 0xFFFF0000u);
}
__device__ __forceinline__ u32 pack_bf16x2(float lo, float hi) {
    return ((u32)f32_to_bf16(hi) << 16) | f32_to_bf16(lo);
}

// ---------------------------------------------------------------------------
// init: acc = concat(user,item) (f32);  ego0 = bf16 mirror
// ---------------------------------------------------------------------------
__global__ void lgcn_init_kernel(const float* __restrict__ user_emb,
                                 const float* __restrict__ item_emb,
                                 float* __restrict__ acc,
                                 u16* __restrict__ ego_bf16) {
    const long total4 = (long)N_TOTAL * EMB / 4;
    long idx = (long)blockIdx.x * blockDim.x + threadIdx.x;
    if (idx >= total4) return;
    long e = idx * 4;
    const long user_elems = (long)N_USERS * EMB;
    float4 v;
    if (e < user_elems) {
        v = *(const float4*)(user_emb + e);
    } else {
        v = *(const float4*)(item_emb + (e - user_elems));
    }
    *(float4*)(acc + e) = v;
    ushort4 h;
    h.x = f32_to_bf16(v.x);
    h.y = f32_to_bf16(v.y);
    h.z = f32_to_bf16(v.z);
    h.w = f32_to_bf16(v.w);
    *(ushort4*)(ego_bf16 + e) = h;
}

// ---------------------------------------------------------------------------
// bucket histogram: LDS-staged (per-block private hist, one flush at end)
// ---------------------------------------------------------------------------
#define HIST_EPB 8192   // edges per block

__global__ void lgcn_bhist_kernel(const int* __restrict__ rows,
                                  int* __restrict__ counts) {
    __shared__ int h[BUCKETS];
    const int t = threadIdx.x;
    for (int i = t; i < BUCKETS; i += 256) h[i] = 0;
    __syncthreads();
    const long base = (long)blockIdx.x * HIST_EPB;
    #pragma unroll
    for (int k = 0; k < 8; ++k) {
        long e4 = base + (long)(k * 256 + t) * 4;
        if (e4 < NNZ_CONST) {
            int4 r = *(const int4*)(rows + e4);
            atomicAdd(&h[r.x >> BSHIFT], 1);
            atomicAdd(&h[r.y >> BSHIFT], 1);
            atomicAdd(&h[r.z >> BSHIFT], 1);
            atomicAdd(&h[r.w >> BSHIFT], 1);
        }
    }
    __syncthreads();
    for (int i = t; i < BUCKETS; i += 256) {
        int c = h[i];
        if (c) atomicAdd(&counts[i], c);
    }
}

// ---------------------------------------------------------------------------
// exclusive scan of 2344 bucket counts; single block, 1024 threads, 4/thread.
// counts and cursor may alias (reads complete before first barrier exit).
// ---------------------------------------------------------------------------
__global__ void lgcn_bscan_kernel(const int* __restrict__ counts,
                                  int* __restrict__ bucket_ptr,
                                  int* __restrict__ cursor) {
    __shared__ int lds[1024];
    const int t = threadIdx.x;
    int4 c = make_int4(0, 0, 0, 0);
    if (t < BUCKETS / 4) c = ((const int4*)counts)[t];   // 2344/4 = 586
    const int local = c.x + c.y + c.z + c.w;
    lds[t] = local;
    __syncthreads();
    for (int off = 1; off < 1024; off <<= 1) {
        int v = (t >= off) ? lds[t - off] : 0;
        __syncthreads();
        lds[t] += v;
        __syncthreads();
    }
    const int ex = lds[t] - local;
    if (t < BUCKETS / 4) {
        int4 r;
        r.x = ex;
        r.y = r.x + c.x;
        r.z = r.y + c.y;
        r.w = r.z + c.z;
        ((int4*)bucket_ptr)[t] = r;
        ((int4*)cursor)[t] = r;
    }
    if (t == 1023) bucket_ptr[BUCKETS] = lds[1023];   // = NNZ
}

// ---------------------------------------------------------------------------
// fill: scatter packed pairs into bucket-major order.
// pair = val(f32, hi32) | row_local(6b @18) | col(18b).
// 2344 bucket tails x 64B = 150 KB active lines -> L2 assembles full lines.
// ---------------------------------------------------------------------------
__global__ void lgcn_bfill_kernel(const int* __restrict__ rows,
                                  const int* __restrict__ cols,
                                  const float* __restrict__ vals,
                                  int* __restrict__ cursor,
                                  u64* __restrict__ pairs) {
    long t = (long)blockIdx.x * blockDim.x + threadIdx.x;
    long e4 = t * 4;
    if (e4 >= NNZ_CONST) return;
    int4 r = *(const int4*)(rows + e4);
    int4 c = *(const int4*)(cols + e4);
    float4 v = *(const float4*)(vals + e4);
    {
        int pos = atomicAdd(&cursor[r.x >> BSHIFT], 1);
        pairs[pos] = ((u64)__float_as_uint(v.x) << 32) |
                     ((u32)(r.x & 63) << 18) | (u32)c.x;
    }
    {
        int pos = atomicAdd(&cursor[r.y >> BSHIFT], 1);
        pairs[pos] = ((u64)__float_as_uint(v.y) << 32) |
                     ((u32)(r.y & 63) << 18) | (u32)c.y;
    }
    {
        int pos = atomicAdd(&cursor[r.z >> BSHIFT], 1);
        pairs[pos] = ((u64)__float_as_uint(v.z) << 32) |
                     ((u32)(r.z & 63) << 18) | (u32)c.z;
    }
    {
        int pos = atomicAdd(&cursor[r.w >> BSHIFT], 1);
        pairs[pos] = ((u64)__float_as_uint(v.w) << 32) |
                     ((u32)(r.w & 63) << 18) | (u32)c.w;
    }
}

// ---------------------------------------------------------------------------
// SpMM: one block per bucket. 64x68 f32 LDS accumulator tile.
// 16 edge-slots (4 waves x 4 groups of 16 lanes), unroll x2 = 32 gathers in
// flight. Lane covers 4 dims (uint2 = 4 bf16). LDS f32 atomics accumulate.
// Epilogue: coalesced bf16 dst write + fused f32 acc update (+ final scale).
// ---------------------------------------------------------------------------
__global__ void lgcn_spmm_lds_kernel(const int* __restrict__ bucket_ptr,
                                     const u64* __restrict__ pairs,
                                     const u16* __restrict__ src,
                                     u16* __restrict__ dst,
                                     float* __restrict__ acc,
                                     float scale) {
    __shared__ float lacc[ROWS_PER_BUCKET * LACC_STRIDE];   // 17408 B
    const int t = threadIdx.x;
    // zero the tile (1088 float4s)
    for (int i = t; i < ROWS_PER_BUCKET * LACC_STRIDE / 4; i += 256)
        ((float4*)lacc)[i] = make_float4(0.f, 0.f, 0.f, 0.f);
    __syncthreads();

    const int b = blockIdx.x;
    const int start = bucket_ptr[b];
    const int end   = bucket_ptr[b + 1];
    const int wave = t >> 6;
    const int lane = t & 63;
    const int grp  = lane >> 4;          // 0..3
    const int l16  = lane & 15;          // dims [l16*4, l16*4+4)
    const int slot = wave * 4 + grp;     // 0..15

#define PROCESS(E)                                                          \
    {                                                                       \
        const u64 p = __builtin_nontemporal_load(&pairs[E]);                \
        const u32 lo = (u32)p;                                              \
        const int col = (int)(lo & 0x3FFFFu);                               \
        const int rl  = (int)(lo >> 18);                                    \
        const float v = __uint_as_float((u32)(p >> 32));                    \
        const uint2 x = *(const uint2*)(src + (size_t)col * EMB + l16 * 4); \
        float* lp = lacc + rl * LACC_STRIDE + l16 * 4;                      \
        atomicAdd(lp + 0, v * bf16lo_to_f32(x.x));                          \
        atomicAdd(lp + 1, v * bf16hi_to_f32(x.x));                          \
        atomicAdd(lp + 2, v * bf16lo_to_f32(x.y));                          \
        atomicAdd(lp + 3, v * bf16hi_to_f32(x.y));                          \
    }

    int e = start + slot;
    for (; e + 16 < end; e += 32) {
        PROCESS(e);
        PROCESS(e + 16);
    }
    if (e < end) PROCESS(e);
#undef PROCESS
    __syncthreads();

    // epilogue: 4 threads per row, 16 dims each
    const int row = t >> 2;
    const int q = t & 3;
    const int grow = b * ROWS_PER_BUCKET + row;
    if (grow < N_TOTAL) {
        const float* lp = lacc + row * LACC_STRIDE + q * 16;
        const float4 s0 = *(const float4*)(lp + 0);
        const float4 s1 = *(const float4*)(lp + 4);
        const float4 s2 = *(const float4*)(lp + 8);
        const float4 s3 = *(const float4*)(lp + 12);
        const size_t o = (size_t)grow * EMB + q * 16;
        uint4 h0, h1;
        h0.x = pack_bf16x2(s0.x, s0.y);  h0.y = pack_bf16x2(s0.z, s0.w);
        h0.z = pack_bf16x2(s1.x, s1.y);  h0.w = pack_bf16x2(s1.z, s1.w);
        h1.x = pack_bf16x2(s2.x, s2.y);  h1.y = pack_bf16x2(s2.z, s2.w);
        h1.z = pack_bf16x2(s3.x, s3.y);  h1.w = pack_bf16x2(s3.z, s3.w);
        *(uint4*)(dst + o) = h0;
        *(uint4*)(dst + o + 8) = h1;
        float4 a0 = *(const float4*)(acc + o + 0);
        float4 a1 = *(const float4*)(acc + o + 4);
        float4 a2 = *(const float4*)(acc + o + 8);
        float4 a3 = *(const float4*)(acc + o + 12);
        a0.x = (a0.x + s0.x) * scale; a0.y = (a0.y + s0.y) * scale;
        a0.z = (a0.z + s0.z) * scale; a0.w = (a0.w + s0.w) * scale;
        a1.x = (a1.x + s1.x) * scale; a1.y = (a1.y + s1.y) * scale;
        a1.z = (a1.z + s1.z) * scale; a1.w = (a1.w + s1.w) * scale;
        a2.x = (a2.x + s2.x) * scale; a2.y = (a2.y + s2.y) * scale;
        a2.z = (a2.z + s2.z) * scale; a2.w = (a2.w + s2.w) * scale;
        a3.x = (a3.x + s3.x) * scale; a3.y = (a3.y + s3.y) * scale;
        a3.z = (a3.z + s3.z) * scale; a3.w = (a3.w + s3.w) * scale;
        *(float4*)(acc + o + 0) = a0;
        *(float4*)(acc + o + 4) = a1;
        *(float4*)(acc + o + 8) = a2;
        *(float4*)(acc + o + 12) = a3;
    }
}

extern "C" void kernel_launch(void* const* d_in, const int* in_sizes, int n_in,
                              void* d_out, int out_size, void* d_ws, size_t ws_size,
                              hipStream_t stream) {
    const float* user_emb = (const float*)d_in[0];
    const float* item_emb = (const float*)d_in[1];
    const int*   adj_rows = (const int*)d_in[2];
    const int*   adj_cols = (const int*)d_in[3];
    const float* adj_vals = (const float*)d_in[4];

    float* acc = (float*)d_out;

    // workspace layout
    char* ws = (char*)d_ws;
    u16* egoA = (u16*)ws;           ws += (size_t)N_TOTAL * EMB * 2;   // 19.2 MB
    u16* egoB = (u16*)ws;           ws += (size_t)N_TOTAL * EMB * 2;   // 19.2 MB
    u64* pairs = (u64*)ws;          ws += (size_t)NNZ_CONST * 8;       // 64 MB
    int* bucket_ptr = (int*)ws;     ws += (size_t)(BUCKETS + 8) * 4;
    int* cursor     = (int*)ws;     ws += (size_t)(BUCKETS + 8) * 4;

    const int block = 256;
    const long total4 = (long)N_TOTAL * EMB / 4;
    const int grid_elem = (int)((total4 + block - 1) / block);

    // init acc (f32) + ego0 (bf16)
    lgcn_init_kernel<<<grid_elem, block, 0, stream>>>(user_emb, item_emb, acc, egoA);

    // ---- build bucket-major pairs ----
    (void)hipMemsetAsync(cursor, 0, (size_t)BUCKETS * 4, stream);
    const int grid_hist = (NNZ_CONST + HIST_EPB - 1) / HIST_EPB;   // 977
    lgcn_bhist_kernel<<<grid_hist, 256, 0, stream>>>(adj_rows, cursor);
    lgcn_bscan_kernel<<<1, 1024, 0, stream>>>(cursor, bucket_ptr, cursor);
    const int grid_fill = (NNZ_CONST / 4 + block - 1) / block;     // 7813
    lgcn_bfill_kernel<<<grid_fill, block, 0, stream>>>(adj_rows, adj_cols, adj_vals,
                                                       cursor, pairs);

    // ---- 3 propagation layers ----
    u16* src = egoA;
    u16* dst = egoB;
    for (int layer = 0; layer < 3; ++layer) {
        const float scale = (layer == 2) ? 0.25f : 1.0f;
        lgcn_spmm_lds_kernel<<<BUCKETS, 256, 0, stream>>>(
            bucket_ptr, pairs, src, dst, acc, scale);
        u16* t = src; src = dst; dst = t;
    }
}

// Round 8
// 1410.736 us; speedup vs baseline: 6.5456x; 6.5456x over previous
//
#include <hip/hip_runtime.h>

#define N_USERS 100000
#define N_ITEMS 50000
#define N_TOTAL 150000
#define EMB 64
#define NNZ_CONST 8000000

// bucketing: 64 rows per bucket
#define BSHIFT 6
#define ROWS_PER_BUCKET 64
#define BUCKETS 2344            // ceil(150000/64)
#define SORT_CAP 5120           // bucket mean 3413, sd 58 -> +29 sigma headroom

typedef unsigned short u16;
typedef unsigned int u32;
typedef unsigned long long u64;

// f32 -> bf16 round-to-nearest-even
__device__ __forceinline__ u16 f32_to_bf16(float f) {
    u32 b = __float_as_uint(f);
    b += 0x7FFFu + ((b >> 16) & 1u);
    return (u16)(b >> 16);
}
__device__ __forceinline__ float bf16lo_to_f32(u32 w) {
    return __uint_as_float(w << 16);
}
__device__ __forceinline__ float bf16hi_to_f32(u32 w) {
    return __uint_as_float(w & 0xFFFF0000u);
}
__device__ __forceinline__ u32 pack_bf16x2(float lo, float hi) {
    return ((u32)f32_to_bf16(hi) << 16) | f32_to_bf16(lo);
}

// ---------------------------------------------------------------------------
// init: acc = concat(user,item) (f32);  ego0 = bf16 mirror
// ---------------------------------------------------------------------------
__global__ void lgcn_init_kernel(const float* __restrict__ user_emb,
                                 const float* __restrict__ item_emb,
                                 float* __restrict__ acc,
                                 u16* __restrict__ ego_bf16) {
    const long total4 = (long)N_TOTAL * EMB / 4;
    long idx = (long)blockIdx.x * blockDim.x + threadIdx.x;
    if (idx >= total4) return;
    long e = idx * 4;
    const long user_elems = (long)N_USERS * EMB;
    float4 v;
    if (e < user_elems) {
        v = *(const float4*)(user_emb + e);
    } else {
        v = *(const float4*)(item_emb + (e - user_elems));
    }
    *(float4*)(acc + e) = v;
    ushort4 h;
    h.x = f32_to_bf16(v.x);
    h.y = f32_to_bf16(v.y);
    h.z = f32_to_bf16(v.z);
    h.w = f32_to_bf16(v.w);
    *(ushort4*)(ego_bf16 + e) = h;
}

// ---------------------------------------------------------------------------
// bucket histogram: LDS-staged (per-block private hist, one flush at end)
// ---------------------------------------------------------------------------
#define HIST_EPB 8192   // edges per block

__global__ void lgcn_bhist_kernel(const int* __restrict__ rows,
                                  int* __restrict__ counts) {
    __shared__ int h[BUCKETS];
    const int t = threadIdx.x;
    for (int i = t; i < BUCKETS; i += 256) h[i] = 0;
    __syncthreads();
    const long base = (long)blockIdx.x * HIST_EPB;
    #pragma unroll
    for (int k = 0; k < 8; ++k) {
        long e4 = base + (long)(k * 256 + t) * 4;
        if (e4 < NNZ_CONST) {
            int4 r = *(const int4*)(rows + e4);
            atomicAdd(&h[r.x >> BSHIFT], 1);
            atomicAdd(&h[r.y >> BSHIFT], 1);
            atomicAdd(&h[r.z >> BSHIFT], 1);
            atomicAdd(&h[r.w >> BSHIFT], 1);
        }
    }
    __syncthreads();
    for (int i = t; i < BUCKETS; i += 256) {
        int c = h[i];
        if (c) atomicAdd(&counts[i], c);
    }
}

// ---------------------------------------------------------------------------
// exclusive scan of 2344 bucket counts; single block, 1024 threads, 4/thread
// ---------------------------------------------------------------------------
__global__ void lgcn_bscan_kernel(const int* __restrict__ counts,
                                  int* __restrict__ bucket_ptr,
                                  int* __restrict__ cursor) {
    __shared__ int lds[1024];
    const int t = threadIdx.x;
    int4 c = make_int4(0, 0, 0, 0);
    if (t < BUCKETS / 4) c = ((const int4*)counts)[t];   // 2344/4 = 586
    const int local = c.x + c.y + c.z + c.w;
    lds[t] = local;
    __syncthreads();
    for (int off = 1; off < 1024; off <<= 1) {
        int v = (t >= off) ? lds[t - off] : 0;
        __syncthreads();
        lds[t] += v;
        __syncthreads();
    }
    const int ex = lds[t] - local;
    if (t < BUCKETS / 4) {
        int4 r;
        r.x = ex;
        r.y = r.x + c.x;
        r.z = r.y + c.y;
        r.w = r.z + c.z;
        ((int4*)bucket_ptr)[t] = r;
        ((int4*)cursor)[t] = r;
    }
    if (t == 1023) bucket_ptr[BUCKETS] = lds[1023];   // = NNZ
}

// ---------------------------------------------------------------------------
// fill: scatter packed pairs into bucket-major order.
// pair = val(f32, hi32) | row_local(6b @18) | col(18b).
// 2344 bucket tails x 64B = 150 KB active lines -> L2 assembles full lines.
// ---------------------------------------------------------------------------
__global__ void lgcn_bfill_kernel(const int* __restrict__ rows,
                                  const int* __restrict__ cols,
                                  const float* __restrict__ vals,
                                  int* __restrict__ cursor,
                                  u64* __restrict__ pairs) {
    long t = (long)blockIdx.x * blockDim.x + threadIdx.x;
    long e4 = t * 4;
    if (e4 >= NNZ_CONST) return;
    int4 r = *(const int4*)(rows + e4);
    int4 c = *(const int4*)(cols + e4);
    float4 v = *(const float4*)(vals + e4);
    {
        int pos = atomicAdd(&cursor[r.x >> BSHIFT], 1);
        pairs[pos] = ((u64)__float_as_uint(v.x) << 32) |
                     ((u32)(r.x & 63) << 18) | (u32)c.x;
    }
    {
        int pos = atomicAdd(&cursor[r.y >> BSHIFT], 1);
        pairs[pos] = ((u64)__float_as_uint(v.y) << 32) |
                     ((u32)(r.y & 63) << 18) | (u32)c.y;
    }
    {
        int pos = atomicAdd(&cursor[r.z >> BSHIFT], 1);
        pairs[pos] = ((u64)__float_as_uint(v.z) << 32) |
                     ((u32)(r.z & 63) << 18) | (u32)c.z;
    }
    {
        int pos = atomicAdd(&cursor[r.w >> BSHIFT], 1);
        pairs[pos] = ((u64)__float_as_uint(v.w) << 32) |
                     ((u32)(r.w & 63) << 18) | (u32)c.w;
    }
}

// ---------------------------------------------------------------------------
// per-bucket counting sort (in place via LDS staging) -> full row-sorted
// order, repacked as (val<<32)|col. Also emits row_ptr.
// One block per bucket; bucket edges staged in LDS (cap 5120 = +29 sigma).
// ---------------------------------------------------------------------------
__global__ void lgcn_bsort_kernel(const int* __restrict__ bucket_ptr,
                                  u64* __restrict__ pairs,
                                  int* __restrict__ row_ptr) {
    __shared__ u64 stage[SORT_CAP];               // 40960 B
    __shared__ int hist[ROWS_PER_BUCKET];
    __shared__ int offs[ROWS_PER_BUCKET + 1];
    const int b = blockIdx.x;
    const int t = threadIdx.x;
    const int start = bucket_ptr[b];
    const int n0 = bucket_ptr[b + 1] - start;
    const int n = (n0 < SORT_CAP) ? n0 : SORT_CAP;

    if (t < ROWS_PER_BUCKET) hist[t] = 0;
    __syncthreads();

    for (int i = t; i < n; i += 256) {
        u64 p = pairs[start + i];
        stage[i] = p;
        atomicAdd(&hist[((u32)p >> 18) & 63], 1);
    }
    __syncthreads();

    if (t == 0) {
        int run = 0;
        #pragma unroll
        for (int r = 0; r < ROWS_PER_BUCKET; ++r) { offs[r] = run; run += hist[r]; }
        offs[ROWS_PER_BUCKET] = run;
    }
    __syncthreads();

    if (t < ROWS_PER_BUCKET) {
        int grow = b * ROWS_PER_BUCKET + t;
        if (grow <= N_TOTAL) row_ptr[grow] = start + offs[t];
        hist[t] = offs[t];   // reuse as cursor
    }
    __syncthreads();

    for (int i = t; i < n; i += 256) {
        u64 p = stage[i];
        int rl = (int)(((u32)p >> 18) & 63);
        int pos = atomicAdd(&hist[rl], 1);
        u64 out = (p & 0xFFFFFFFF00000000ull) | ((u32)p & 0x3FFFFu);
        pairs[start + pos] = out;
    }
}

// ---------------------------------------------------------------------------
// Gather SpMM (bf16 src) + fused f32 accumulate, bf16 dst for next layer.
// One wave per row; 8 groups x 8 lanes. Each lane loads 8 bf16 dims (16B).
// Hand-unrolled x2 => 16 edges in flight per wave. Cross-group shfl reduce.
// ---------------------------------------------------------------------------
__global__ void lgcn_spmm_kernel(const int* __restrict__ row_ptr,
                                 const u64* __restrict__ pairs,
                                 const u16* __restrict__ src,
                                 u16* __restrict__ dst,
                                 float* __restrict__ acc,
                                 float scale) {
    const int wave = threadIdx.x >> 6;
    const int lane = threadIdx.x & 63;
    const int grp  = lane >> 3;     // 0..7 : edge slot within 8-batch
    const int l8   = lane & 7;      // dims [l8*8, l8*8+8)
    const int row = blockIdx.x * 4 + wave;
    if (row >= N_TOTAL) return;
    const int start = row_ptr[row];
    const int end   = row_ptr[row + 1];

    float4 a0 = make_float4(0.f, 0.f, 0.f, 0.f);
    float4 a1 = make_float4(0.f, 0.f, 0.f, 0.f);
    float4 b0 = make_float4(0.f, 0.f, 0.f, 0.f);
    float4 b1 = make_float4(0.f, 0.f, 0.f, 0.f);

    int e = start + grp;
    for (; e + 8 < end; e += 16) {
        const u64 p0 = __builtin_nontemporal_load(&pairs[e]);
        const u64 p1 = __builtin_nontemporal_load(&pairs[e + 8]);
        const int   c0 = (int)(u32)(p0 & 0xFFFFFFFFull);
        const float v0 = __uint_as_float((u32)(p0 >> 32));
        const int   c1 = (int)(u32)(p1 & 0xFFFFFFFFull);
        const float v1 = __uint_as_float((u32)(p1 >> 32));
        const uint4 x0 = *(const uint4*)(src + (size_t)c0 * EMB + l8 * 8);
        const uint4 x1 = *(const uint4*)(src + (size_t)c1 * EMB + l8 * 8);
        a0.x += v0 * bf16lo_to_f32(x0.x);  a0.y += v0 * bf16hi_to_f32(x0.x);
        a0.z += v0 * bf16lo_to_f32(x0.y);  a0.w += v0 * bf16hi_to_f32(x0.y);
        a1.x += v0 * bf16lo_to_f32(x0.z);  a1.y += v0 * bf16hi_to_f32(x0.z);
        a1.z += v0 * bf16lo_to_f32(x0.w);  a1.w += v0 * bf16hi_to_f32(x0.w);
        b0.x += v1 * bf16lo_to_f32(x1.x);  b0.y += v1 * bf16hi_to_f32(x1.x);
        b0.z += v1 * bf16lo_to_f32(x1.y);  b0.w += v1 * bf16hi_to_f32(x1.y);
        b1.x += v1 * bf16lo_to_f32(x1.z);  b1.y += v1 * bf16hi_to_f32(x1.z);
        b1.z += v1 * bf16lo_to_f32(x1.w);  b1.w += v1 * bf16hi_to_f32(x1.w);
    }
    if (e < end) {
        const u64 p0 = __builtin_nontemporal_load(&pairs[e]);
        const int   c0 = (int)(u32)(p0 & 0xFFFFFFFFull);
        const float v0 = __uint_as_float((u32)(p0 >> 32));
        const uint4 x0 = *(const uint4*)(src + (size_t)c0 * EMB + l8 * 8);
        a0.x += v0 * bf16lo_to_f32(x0.x);  a0.y += v0 * bf16hi_to_f32(x0.x);
        a0.z += v0 * bf16lo_to_f32(x0.y);  a0.w += v0 * bf16hi_to_f32(x0.y);
        a1.x += v0 * bf16lo_to_f32(x0.z);  a1.y += v0 * bf16hi_to_f32(x0.z);
        a1.z += v0 * bf16lo_to_f32(x0.w);  a1.w += v0 * bf16hi_to_f32(x0.w);
    }
    a0.x += b0.x; a0.y += b0.y; a0.z += b0.z; a0.w += b0.w;
    a1.x += b1.x; a1.y += b1.y; a1.z += b1.z; a1.w += b1.w;

    #pragma unroll
    for (int m = 8; m <= 32; m <<= 1) {
        a0.x += __shfl_xor(a0.x, m); a0.y += __shfl_xor(a0.y, m);
        a0.z += __shfl_xor(a0.z, m); a0.w += __shfl_xor(a0.w, m);
        a1.x += __shfl_xor(a1.x, m); a1.y += __shfl_xor(a1.y, m);
        a1.z += __shfl_xor(a1.z, m); a1.w += __shfl_xor(a1.w, m);
    }

    if (grp == 0) {
        const size_t o = (size_t)row * EMB + l8 * 8;
        uint4 h;
        h.x = pack_bf16x2(a0.x, a0.y);
        h.y = pack_bf16x2(a0.z, a0.w);
        h.z = pack_bf16x2(a1.x, a1.y);
        h.w = pack_bf16x2(a1.z, a1.w);
        *(uint4*)(dst + o) = h;
        float4 p = *(const float4*)(acc + o);
        float4 q = *(const float4*)(acc + o + 4);
        p.x = (p.x + a0.x) * scale; p.y = (p.y + a0.y) * scale;
        p.z = (p.z + a0.z) * scale; p.w = (p.w + a0.w) * scale;
        q.x = (q.x + a1.x) * scale; q.y = (q.y + a1.y) * scale;
        q.z = (q.z + a1.z) * scale; q.w = (q.w + a1.w) * scale;
        *(float4*)(acc + o) = p;
        *(float4*)(acc + o + 4) = q;
    }
}

extern "C" void kernel_launch(void* const* d_in, const int* in_sizes, int n_in,
                              void* d_out, int out_size, void* d_ws, size_t ws_size,
                              hipStream_t stream) {
    const float* user_emb = (const float*)d_in[0];
    const float* item_emb = (const float*)d_in[1];
    const int*   adj_rows = (const int*)d_in[2];
    const int*   adj_cols = (const int*)d_in[3];
    const float* adj_vals = (const float*)d_in[4];

    float* acc = (float*)d_out;

    // workspace layout
    char* ws = (char*)d_ws;
    u16* egoA = (u16*)ws;           ws += (size_t)N_TOTAL * EMB * 2;   // 19.2 MB
    u16* egoB = (u16*)ws;           ws += (size_t)N_TOTAL * EMB * 2;   // 19.2 MB
    u64* pairs = (u64*)ws;          ws += (size_t)NNZ_CONST * 8;       // 64 MB
    int* bucket_ptr = (int*)ws;     ws += (size_t)(BUCKETS + 8) * 4;
    int* cursor     = (int*)ws;     ws += (size_t)(BUCKETS + 8) * 4;
    int* row_ptr    = (int*)ws;     ws += (size_t)(N_TOTAL + 16) * 4;

    const int block = 256;
    const long total4 = (long)N_TOTAL * EMB / 4;
    const int grid_elem = (int)((total4 + block - 1) / block);

    // init acc (f32) + ego0 (bf16)
    lgcn_init_kernel<<<grid_elem, block, 0, stream>>>(user_emb, item_emb, acc, egoA);

    // ---- build row-sorted pairs: bucket fill + per-bucket counting sort ----
    (void)hipMemsetAsync(cursor, 0, (size_t)BUCKETS * 4, stream);
    const int grid_hist = (NNZ_CONST + HIST_EPB - 1) / HIST_EPB;   // 977
    lgcn_bhist_kernel<<<grid_hist, 256, 0, stream>>>(adj_rows, cursor);
    lgcn_bscan_kernel<<<1, 1024, 0, stream>>>(cursor, bucket_ptr, cursor);
    const int grid_fill = (NNZ_CONST / 4 + block - 1) / block;     // 7813
    lgcn_bfill_kernel<<<grid_fill, block, 0, stream>>>(adj_rows, adj_cols, adj_vals,
                                                       cursor, pairs);
    lgcn_bsort_kernel<<<BUCKETS, 256, 0, stream>>>(bucket_ptr, pairs, row_ptr);

    // ---- 3 propagation layers ----
    const int grid_spmm = (N_TOTAL + 3) / 4;
    u16* src = egoA;
    u16* dst = egoB;
    for (int layer = 0; layer < 3; ++layer) {
        const float scale = (layer == 2) ? 0.25f : 1.0f;
        lgcn_spmm_kernel<<<grid_spmm, block, 0, stream>>>(
            row_ptr, pairs, src, dst, acc, scale);
        u16* t = src; src = dst; dst = t;
    }
}

// Round 9
// 1014.818 us; speedup vs baseline: 9.0993x; 1.3901x over previous
//
#include <hip/hip_runtime.h>

#define N_USERS 100000
#define N_ITEMS 50000
#define N_TOTAL 150000
#define EMB 64
#define NNZ_CONST 8000000

// bucketing: 64 rows per bucket
#define BSHIFT 6
#define ROWS_PER_BUCKET 64
#define BUCKETS 2344            // ceil(150000/64)
#define SORT_CAP 5120           // bucket mean 3413, sd 58 -> +29 sigma headroom
#define NSHARD 8                // one per XCD (blockIdx & 7 ~ XCD round-robin)
#define NSEG (BUCKETS * NSHARD) // 18752 segments
#define HIST_EPB 8192           // edges per hist/fill block

typedef unsigned short u16;
typedef unsigned int u32;
typedef unsigned long long u64;

// f32 -> bf16 round-to-nearest-even
__device__ __forceinline__ u16 f32_to_bf16(float f) {
    u32 b = __float_as_uint(f);
    b += 0x7FFFu + ((b >> 16) & 1u);
    return (u16)(b >> 16);
}
__device__ __forceinline__ float bf16lo_to_f32(u32 w) {
    return __uint_as_float(w << 16);
}
__device__ __forceinline__ float bf16hi_to_f32(u32 w) {
    return __uint_as_float(w & 0xFFFF0000u);
}
__device__ __forceinline__ u32 pack_bf16x2(float lo, float hi) {
    return ((u32)f32_to_bf16(hi) << 16) | f32_to_bf16(lo);
}

// ---------------------------------------------------------------------------
// init: acc = concat(user,item) (f32);  ego0 = bf16 mirror
// ---------------------------------------------------------------------------
__global__ void lgcn_init_kernel(const float* __restrict__ user_emb,
                                 const float* __restrict__ item_emb,
                                 float* __restrict__ acc,
                                 u16* __restrict__ ego_bf16) {
    const long total4 = (long)N_TOTAL * EMB / 4;
    long idx = (long)blockIdx.x * blockDim.x + threadIdx.x;
    if (idx >= total4) return;
    long e = idx * 4;
    const long user_elems = (long)N_USERS * EMB;
    float4 v;
    if (e < user_elems) {
        v = *(const float4*)(user_emb + e);
    } else {
        v = *(const float4*)(item_emb + (e - user_elems));
    }
    *(float4*)(acc + e) = v;
    ushort4 h;
    h.x = f32_to_bf16(v.x);
    h.y = f32_to_bf16(v.y);
    h.z = f32_to_bf16(v.z);
    h.w = f32_to_bf16(v.w);
    *(ushort4*)(ego_bf16 + e) = h;
}

// ---------------------------------------------------------------------------
// per-(bucket,shard) histogram. Block b covers edges [b*8192,(b+1)*8192),
// shard = b & 7. LDS-private hist, one strided flush.
// ---------------------------------------------------------------------------
__global__ void lgcn_bhist_kernel(const int* __restrict__ rows,
                                  int* __restrict__ counts) {
    __shared__ int h[BUCKETS];
    const int t = threadIdx.x;
    const int shard = blockIdx.x & (NSHARD - 1);
    for (int i = t; i < BUCKETS; i += 256) h[i] = 0;
    __syncthreads();
    const long base = (long)blockIdx.x * HIST_EPB;
    #pragma unroll
    for (int k = 0; k < 8; ++k) {
        long e4 = base + (long)(k * 256 + t) * 4;
        if (e4 < NNZ_CONST) {
            int4 r = *(const int4*)(rows + e4);
            atomicAdd(&h[r.x >> BSHIFT], 1);
            atomicAdd(&h[r.y >> BSHIFT], 1);
            atomicAdd(&h[r.z >> BSHIFT], 1);
            atomicAdd(&h[r.w >> BSHIFT], 1);
        }
    }
    __syncthreads();
    for (int i = t; i < BUCKETS; i += 256) {
        int c = h[i];
        if (c) atomicAdd(&counts[(i << 3) | shard], c);
    }
}

// ---------------------------------------------------------------------------
// exclusive scan of 18752 segment counts (layout [bucket][shard]).
// Single block, 1024 threads, 19 serial elements each + LDS Hillis-Steele.
// counts/cursor may alias seg-wise (each thread reads its chunk before the
// barriers, writes it after).
// ---------------------------------------------------------------------------
__global__ void lgcn_sscan_kernel(const int* __restrict__ counts,
                                  int* __restrict__ seg_ptr,
                                  int* __restrict__ cursor) {
    __shared__ int lds[1024];
    const int t = threadIdx.x;
    const int CH = (NSEG + 1023) / 1024;   // 19
    const int begin = t * CH;
    const int endi = min(begin + CH, NSEG);
    int local = 0;
    for (int i = begin; i < endi; ++i) local += counts[i];
    lds[t] = local;
    __syncthreads();
    for (int off = 1; off < 1024; off <<= 1) {
        int v = (t >= off) ? lds[t - off] : 0;
        __syncthreads();
        lds[t] += v;
        __syncthreads();
    }
    int run = lds[t] - local;
    for (int i = begin; i < endi; ++i) {
        int c = counts[i];
        seg_ptr[i] = run;
        cursor[i]  = run;
        run += c;
    }
    if (t == 1023) seg_ptr[NSEG] = run;   // = NNZ
}

// ---------------------------------------------------------------------------
// fill: scatter packed pairs into (bucket,shard)-major order.
// pair = val(f32, hi32) | row_local(6b @18) | col(18b).
// All writes to a segment come from one XCD (shard = blockIdx&7), so that
// XCD's L2 assembles full 64B lines -> ~1x write amplification.
// ---------------------------------------------------------------------------
__global__ void lgcn_bfill_kernel(const int* __restrict__ rows,
                                  const int* __restrict__ cols,
                                  const float* __restrict__ vals,
                                  int* __restrict__ cursor,
                                  u64* __restrict__ pairs) {
    const int t = threadIdx.x;
    const int shard = blockIdx.x & (NSHARD - 1);
    const long base = (long)blockIdx.x * HIST_EPB;
    #pragma unroll
    for (int k = 0; k < 8; ++k) {
        long e4 = base + (long)(k * 256 + t) * 4;
        if (e4 < NNZ_CONST) {
            int4 r = *(const int4*)(rows + e4);
            int4 c = *(const int4*)(cols + e4);
            float4 v = *(const float4*)(vals + e4);
            {
                int pos = atomicAdd(&cursor[((r.x >> BSHIFT) << 3) | shard], 1);
                pairs[pos] = ((u64)__float_as_uint(v.x) << 32) |
                             ((u32)(r.x & 63) << 18) | (u32)c.x;
            }
            {
                int pos = atomicAdd(&cursor[((r.y >> BSHIFT) << 3) | shard], 1);
                pairs[pos] = ((u64)__float_as_uint(v.y) << 32) |
                             ((u32)(r.y & 63) << 18) | (u32)c.y;
            }
            {
                int pos = atomicAdd(&cursor[((r.z >> BSHIFT) << 3) | shard], 1);
                pairs[pos] = ((u64)__float_as_uint(v.z) << 32) |
                             ((u32)(r.z & 63) << 18) | (u32)c.z;
            }
            {
                int pos = atomicAdd(&cursor[((r.w >> BSHIFT) << 3) | shard], 1);
                pairs[pos] = ((u64)__float_as_uint(v.w) << 32) |
                             ((u32)(r.w & 63) << 18) | (u32)c.w;
            }
        }
    }
}

// ---------------------------------------------------------------------------
// per-bucket counting sort (in place via LDS staging) -> full row-sorted
// order, repacked as (val<<32)|col. Also emits row_ptr.
// Bucket region is contiguous: [seg_ptr[b*8], seg_ptr[(b+1)*8]).
// ---------------------------------------------------------------------------
__global__ void lgcn_bsort_kernel(const int* __restrict__ seg_ptr,
                                  u64* __restrict__ pairs,
                                  int* __restrict__ row_ptr) {
    __shared__ u64 stage[SORT_CAP];               // 40960 B
    __shared__ int hist[ROWS_PER_BUCKET];
    __shared__ int offs[ROWS_PER_BUCKET + 1];
    const int b = blockIdx.x;
    const int t = threadIdx.x;
    const int start = seg_ptr[b << 3];
    const int n0 = seg_ptr[(b + 1) << 3] - start;
    const int n = (n0 < SORT_CAP) ? n0 : SORT_CAP;

    if (t < ROWS_PER_BUCKET) hist[t] = 0;
    __syncthreads();

    for (int i = t; i < n; i += 256) {
        u64 p = pairs[start + i];
        stage[i] = p;
        atomicAdd(&hist[((u32)p >> 18) & 63], 1);
    }
    __syncthreads();

    if (t == 0) {
        int run = 0;
        #pragma unroll
        for (int r = 0; r < ROWS_PER_BUCKET; ++r) { offs[r] = run; run += hist[r]; }
        offs[ROWS_PER_BUCKET] = run;
    }
    __syncthreads();

    if (t < ROWS_PER_BUCKET) {
        int grow = b * ROWS_PER_BUCKET + t;
        if (grow <= N_TOTAL) row_ptr[grow] = start + offs[t];
        hist[t] = offs[t];   // reuse as cursor
    }
    __syncthreads();

    for (int i = t; i < n; i += 256) {
        u64 p = stage[i];
        int rl = (int)(((u32)p >> 18) & 63);
        int pos = atomicAdd(&hist[rl], 1);
        u64 out = (p & 0xFFFFFFFF00000000ull) | ((u32)p & 0x3FFFFu);
        pairs[start + pos] = out;
    }
}

// ---------------------------------------------------------------------------
// Gather SpMM (bf16 src) + fused f32 accumulate, bf16 dst for next layer.
// One wave per row; 8 groups x 8 lanes. Each lane loads 8 bf16 dims (16B).
// Hand-unrolled x2 => 16 edges in flight per wave. Cross-group shfl reduce.
// ---------------------------------------------------------------------------
__global__ void lgcn_spmm_kernel(const int* __restrict__ row_ptr,
                                 const u64* __restrict__ pairs,
                                 const u16* __restrict__ src,
                                 u16* __restrict__ dst,
                                 float* __restrict__ acc,
                                 float scale) {
    const int wave = threadIdx.x >> 6;
    const int lane = threadIdx.x & 63;
    const int grp  = lane >> 3;     // 0..7 : edge slot within 8-batch
    const int l8   = lane & 7;      // dims [l8*8, l8*8+8)
    const int row = blockIdx.x * 4 + wave;
    if (row >= N_TOTAL) return;
    const int start = row_ptr[row];
    const int end   = row_ptr[row + 1];

    float4 a0 = make_float4(0.f, 0.f, 0.f, 0.f);
    float4 a1 = make_float4(0.f, 0.f, 0.f, 0.f);
    float4 b0 = make_float4(0.f, 0.f, 0.f, 0.f);
    float4 b1 = make_float4(0.f, 0.f, 0.f, 0.f);

    int e = start + grp;
    for (; e + 8 < end; e += 16) {
        const u64 p0 = __builtin_nontemporal_load(&pairs[e]);
        const u64 p1 = __builtin_nontemporal_load(&pairs[e + 8]);
        const int   c0 = (int)(u32)(p0 & 0xFFFFFFFFull);
        const float v0 = __uint_as_float((u32)(p0 >> 32));
        const int   c1 = (int)(u32)(p1 & 0xFFFFFFFFull);
        const float v1 = __uint_as_float((u32)(p1 >> 32));
        const uint4 x0 = *(const uint4*)(src + (size_t)c0 * EMB + l8 * 8);
        const uint4 x1 = *(const uint4*)(src + (size_t)c1 * EMB + l8 * 8);
        a0.x += v0 * bf16lo_to_f32(x0.x);  a0.y += v0 * bf16hi_to_f32(x0.x);
        a0.z += v0 * bf16lo_to_f32(x0.y);  a0.w += v0 * bf16hi_to_f32(x0.y);
        a1.x += v0 * bf16lo_to_f32(x0.z);  a1.y += v0 * bf16hi_to_f32(x0.z);
        a1.z += v0 * bf16lo_to_f32(x0.w);  a1.w += v0 * bf16hi_to_f32(x0.w);
        b0.x += v1 * bf16lo_to_f32(x1.x);  b0.y += v1 * bf16hi_to_f32(x1.x);
        b0.z += v1 * bf16lo_to_f32(x1.y);  b0.w += v1 * bf16hi_to_f32(x1.y);
        b1.x += v1 * bf16lo_to_f32(x1.z);  b1.y += v1 * bf16hi_to_f32(x1.z);
        b1.z += v1 * bf16lo_to_f32(x1.w);  b1.w += v1 * bf16hi_to_f32(x1.w);
    }
    if (e < end) {
        const u64 p0 = __builtin_nontemporal_load(&pairs[e]);
        const int   c0 = (int)(u32)(p0 & 0xFFFFFFFFull);
        const float v0 = __uint_as_float((u32)(p0 >> 32));
        const uint4 x0 = *(const uint4*)(src + (size_t)c0 * EMB + l8 * 8);
        a0.x += v0 * bf16lo_to_f32(x0.x);  a0.y += v0 * bf16hi_to_f32(x0.x);
        a0.z += v0 * bf16lo_to_f32(x0.y);  a0.w += v0 * bf16hi_to_f32(x0.y);
        a1.x += v0 * bf16lo_to_f32(x0.z);  a1.y += v0 * bf16hi_to_f32(x0.z);
        a1.z += v0 * bf16lo_to_f32(x0.w);  a1.w += v0 * bf16hi_to_f32(x0.w);
    }
    a0.x += b0.x; a0.y += b0.y; a0.z += b0.z; a0.w += b0.w;
    a1.x += b1.x; a1.y += b1.y; a1.z += b1.z; a1.w += b1.w;

    #pragma unroll
    for (int m = 8; m <= 32; m <<= 1) {
        a0.x += __shfl_xor(a0.x, m); a0.y += __shfl_xor(a0.y, m);
        a0.z += __shfl_xor(a0.z, m); a0.w += __shfl_xor(a0.w, m);
        a1.x += __shfl_xor(a1.x, m); a1.y += __shfl_xor(a1.y, m);
        a1.z += __shfl_xor(a1.z, m); a1.w += __shfl_xor(a1.w, m);
    }

    if (grp == 0) {
        const size_t o = (size_t)row * EMB + l8 * 8;
        uint4 h;
        h.x = pack_bf16x2(a0.x, a0.y);
        h.y = pack_bf16x2(a0.z, a0.w);
        h.z = pack_bf16x2(a1.x, a1.y);
        h.w = pack_bf16x2(a1.z, a1.w);
        *(uint4*)(dst + o) = h;
        float4 p = *(const float4*)(acc + o);
        float4 q = *(const float4*)(acc + o + 4);
        p.x = (p.x + a0.x) * scale; p.y = (p.y + a0.y) * scale;
        p.z = (p.z + a0.z) * scale; p.w = (p.w + a0.w) * scale;
        q.x = (q.x + a1.x) * scale; q.y = (q.y + a1.y) * scale;
        q.z = (q.z + a1.z) * scale; q.w = (q.w + a1.w) * scale;
        *(float4*)(acc + o) = p;
        *(float4*)(acc + o + 4) = q;
    }
}

extern "C" void kernel_launch(void* const* d_in, const int* in_sizes, int n_in,
                              void* d_out, int out_size, void* d_ws, size_t ws_size,
                              hipStream_t stream) {
    const float* user_emb = (const float*)d_in[0];
    const float* item_emb = (const float*)d_in[1];
    const int*   adj_rows = (const int*)d_in[2];
    const int*   adj_cols = (const int*)d_in[3];
    const float* adj_vals = (const float*)d_in[4];

    float* acc = (float*)d_out;

    // workspace layout
    char* ws = (char*)d_ws;
    u16* egoA = (u16*)ws;           ws += (size_t)N_TOTAL * EMB * 2;   // 19.2 MB
    u16* egoB = (u16*)ws;           ws += (size_t)N_TOTAL * EMB * 2;   // 19.2 MB
    u64* pairs = (u64*)ws;          ws += (size_t)NNZ_CONST * 8;       // 64 MB
    int* seg_ptr = (int*)ws;        ws += (size_t)(NSEG + 8) * 4;
    int* cursor  = (int*)ws;        ws += (size_t)(NSEG + 8) * 4;
    int* row_ptr = (int*)ws;        ws += (size_t)(N_TOTAL + 16) * 4;

    const int block = 256;
    const long total4 = (long)N_TOTAL * EMB / 4;
    const int grid_elem = (int)((total4 + block - 1) / block);

    // init acc (f32) + ego0 (bf16)
    lgcn_init_kernel<<<grid_elem, block, 0, stream>>>(user_emb, item_emb, acc, egoA);

    // ---- build row-sorted pairs: XCD-sharded bucket fill + counting sort ----
    (void)hipMemsetAsync(cursor, 0, (size_t)NSEG * 4, stream);
    const int grid_epb = (NNZ_CONST + HIST_EPB - 1) / HIST_EPB;   // 977
    lgcn_bhist_kernel<<<grid_epb, 256, 0, stream>>>(adj_rows, cursor);
    lgcn_sscan_kernel<<<1, 1024, 0, stream>>>(cursor, seg_ptr, cursor);
    lgcn_bfill_kernel<<<grid_epb, 256, 0, stream>>>(adj_rows, adj_cols, adj_vals,
                                                    cursor, pairs);
    lgcn_bsort_kernel<<<BUCKETS, 256, 0, stream>>>(seg_ptr, pairs, row_ptr);

    // ---- 3 propagation layers ----
    const int grid_spmm = (N_TOTAL + 3) / 4;
    u16* src = egoA;
    u16* dst = egoB;
    for (int layer = 0; layer < 3; ++layer) {
        const float scale = (layer == 2) ? 0.25f : 1.0f;
        lgcn_spmm_kernel<<<grid_spmm, block, 0, stream>>>(
            row_ptr, pairs, src, dst, acc, scale);
        u16* t = src; src = dst; dst = t;
    }
}